// Round 26
// baseline (145.308 us; speedup 1.0000x reference)
//
#include <hip/hip_runtime.h>

#define USH unsigned short

using s8v = __attribute__((ext_vector_type(8))) short;   // 8 x bf16 (4 VGPR)
using f4v = __attribute__((ext_vector_type(4))) float;   // MFMA accumulator

#define MFMA16(a,b,c) __builtin_amdgcn_mfma_f32_16x16x32_bf16(a,b,c,0,0,0)

// dims: B=4, F=T=1024, C=1024, H=16, D=64

__device__ __forceinline__ USH f2bf(float f) {            // RNE f32->bf16
  unsigned int u = __builtin_bit_cast(unsigned int, f);
  u += 0x7fffu + ((u >> 16) & 1u);
  return (USH)(u >> 16);
}
__device__ __forceinline__ unsigned cvtpk(float lo, float hi) { // 2xf32 -> packed bf16 (RNE)
  unsigned r;
  asm("v_cvt_pk_bf16_f32 %0, %1, %2" : "=v"(r) : "v"(lo), "v"(hi));
  return r;
}
__device__ __forceinline__ void gload16(const void* g, void* l) {
  __builtin_amdgcn_global_load_lds((const __attribute__((address_space(1))) void*)g,
                                   (__attribute__((address_space(3))) void*)l, 16, 0, 0);
}

// ---------------- fused pre-pass: qkv cvt (y=0..2), weight cvt (y=3..6), mask pack (y=7) ----------------
__global__ __launch_bounds__(256) void cvt_all_k(
    const float* __restrict__ q, const float* __restrict__ k, const float* __restrict__ v,
    const float* __restrict__ Wq, const float* __restrict__ Wk,
    const float* __restrict__ Wv, const float* __restrict__ Wo,
    const int* __restrict__ mask,
    USH* __restrict__ oq, USH* __restrict__ ok, USH* __restrict__ ov,
    USH* __restrict__ oWq, USH* __restrict__ oWk, USH* __restrict__ oWv, USH* __restrict__ oWo,
    unsigned* __restrict__ omask) {
  const int which = blockIdx.y;
  const int i = blockIdx.x * 256 + threadIdx.x;
  if (which == 7) {                                       // mask pack: 131072 words
    if (i >= 131072) return;
    const int4* p = (const int4*)(mask + i * 32);
    unsigned m = 0;
#pragma unroll
    for (int qq = 0; qq < 8; ++qq) {
      int4 vv = p[qq];
      m |= (unsigned)(vv.x != 0) << (qq * 4);
      m |= (unsigned)(vv.y != 0) << (qq * 4 + 1);
      m |= (unsigned)(vv.z != 0) << (qq * 4 + 2);
      m |= (unsigned)(vv.w != 0) << (qq * 4 + 3);
    }
    omask[i] = m;
    return;
  }
  const float* in; USH* out; int n4;
  switch (which) {
    case 0: in = q;  out = oq;  n4 = 1 << 20; break;
    case 1: in = k;  out = ok;  n4 = 1 << 20; break;
    case 2: in = v;  out = ov;  n4 = 1 << 20; break;
    case 3: in = Wq; out = oWq; n4 = 1 << 18; break;
    case 4: in = Wk; out = oWk; n4 = 1 << 18; break;
    case 5: in = Wv; out = oWv; n4 = 1 << 18; break;
    default: in = Wo; out = oWo; n4 = 1 << 18; break;
  }
  if (i >= n4) return;
  float4 val = ((const float4*)in)[i];
  ushort4 o; o.x = f2bf(val.x); o.y = f2bf(val.y); o.z = f2bf(val.z); o.w = f2bf(val.w);
  ((ushort4*)out)[i] = o;
}

// ---------------- GEMM core: 128x128 tile, BK=32, 512 threads = 8 waves (2x4), B^T layout ----------------
__device__ __forceinline__ void gemm_mainloop8(
    const USH* __restrict__ A, const USH* __restrict__ W,
    int rowA0, int colW0, USH* As, USH* Bs, f4v acc[4][2], int tid) {
  const int lane = tid & 63;
  const int wid = tid >> 6;
  const int l15 = lane & 15, lg = lane >> 4;
  const int wr = (wid >> 2) * 64, wc = (wid & 3) * 32;
  const int srow = tid >> 2, scol = (tid & 3) * 8;
  for (int kk = 0; kk < 32; ++kk) {
    const int k0 = kk * 32;
    gload16(A + (rowA0 + srow) * 1024 + k0 + scol, As + tid * 8);
    gload16(W + (colW0 + srow) * 1024 + k0 + scol, Bs + tid * 8);
    __syncthreads();
    s8v a[4], b[2];
    const USH* ap = As + (wr + l15) * 32 + lg * 8;
    const USH* bp = Bs + (wc + l15) * 32 + lg * 8;
#pragma unroll
    for (int m = 0; m < 4; ++m) a[m] = *(const s8v*)(ap + m * 512);
#pragma unroll
    for (int n = 0; n < 2; ++n) b[n] = *(const s8v*)(bp + n * 512);
#pragma unroll
    for (int m = 0; m < 4; ++m)
#pragma unroll
      for (int n = 0; n < 2; ++n)
        acc[m][n] = MFMA16(a[m], b[n], acc[m][n]);
    __syncthreads();
  }
}

// fused Q/K/V projection; z selects which. Q/K -> [B,H,S,64]; V -> [B,H,64,T] (transposed,
// written coalesced via per-wave LDS transpose)
__global__ __launch_bounds__(512) void proj_gemm_k(
    const USH* __restrict__ qb, const USH* __restrict__ kb, const USH* __restrict__ vb,
    const USH* __restrict__ Wq, const USH* __restrict__ Wk, const USH* __restrict__ Wv,
    const float* __restrict__ bq, const float* __restrict__ bk, const float* __restrict__ bv,
    USH* __restrict__ qh, USH* __restrict__ kh, USH* __restrict__ vT) {
  __shared__ USH As[128 * 32];
  __shared__ USH Bs[128 * 32];
  __shared__ USH Vt[8][32 * 72];        // per-wave transpose stage [d 32][s 64] pad 72
  const int z = blockIdx.z;
  const USH* A = z == 0 ? qb : (z == 1 ? kb : vb);
  const USH* W = z == 0 ? Wq : (z == 1 ? Wk : Wv);
  const float* bias = z == 0 ? bq : (z == 1 ? bk : bv);
  f4v acc[4][2];
#pragma unroll
  for (int m = 0; m < 4; ++m)
#pragma unroll
    for (int n = 0; n < 2; ++n) acc[m][n] = f4v{0.f, 0.f, 0.f, 0.f};
  gemm_mainloop8(A, W, blockIdx.y * 128, blockIdx.x * 128, As, Bs, acc, threadIdx.x);
  const int lane = threadIdx.x & 63, wid = threadIdx.x >> 6;
  const int l15 = lane & 15, lg = lane >> 4;
  const int row0 = blockIdx.y * 128 + (wid >> 2) * 64 + lg * 4;
  const int col0 = blockIdx.x * 128 + (wid & 3) * 32 + l15;
  if (z < 2) {
    USH* qk_dst = (z == 0) ? qh : kh;
#pragma unroll
    for (int n = 0; n < 2; ++n) {
      const int co = col0 + n * 16;
      const float bsv = bias[co];
      const int hh = co >> 6, d = co & 63;
#pragma unroll
      for (int m = 0; m < 4; ++m)
#pragma unroll
        for (int j = 0; j < 4; ++j) {
          const int rr = row0 + m * 16 + j;
          const float v = acc[m][n][j] + bsv;
          const int bb = rr >> 10, s = rr & 1023;
          qk_dst[((bb * 16 + hh) << 16) + (s << 6) + d] = f2bf(v);
        }
    }
  } else {
    // stage acc (+bias) into per-wave LDS as [d_local][s_local]
    USH* st = &Vt[wid][0];
#pragma unroll
    for (int n = 0; n < 2; ++n) {
      const float bsv = bias[col0 + n * 16];
#pragma unroll
      for (int m = 0; m < 4; ++m) {
        uint2 pk;
        pk.x = cvtpk(acc[m][n][0] + bsv, acc[m][n][1] + bsv);
        pk.y = cvtpk(acc[m][n][2] + bsv, acc[m][n][3] + bsv);
        *(uint2*)(st + (n * 16 + l15) * 72 + m * 16 + lg * 4) = pk;
      }
    }
    // read d-rows, store coalesced 8B: each instr = 4 dense 128B segments
    const int srow0 = blockIdx.y * 128 + (wid >> 2) * 64;   // wave's 64 s-rows (one b)
    const int colw0 = blockIdx.x * 128 + (wid & 3) * 32;    // wave's 32 d-cols (one head)
    const int bb = srow0 >> 10, s0 = srow0 & 1023;
    const int hh = colw0 >> 6, d0 = colw0 & 63;
    USH* vout = vT + ((bb * 16 + hh) << 16) + (d0 << 10) + s0;
#pragma unroll
    for (int it = 0; it < 8; ++it) {
      const int d_l = it * 4 + lg;
      const uint2 v = *(const uint2*)(st + d_l * 72 + l15 * 4);
      *(uint2*)(vout + (d_l << 10) + l15 * 4) = v;
    }
  }
}

// output projection: d_out = ctx @ Wo^T + bo  (f32 out)
__global__ __launch_bounds__(512) void out_gemm_k(
    const USH* __restrict__ ctx, const USH* __restrict__ Wo,
    const float* __restrict__ bo, float* __restrict__ out) {
  __shared__ USH As[128 * 32];
  __shared__ USH Bs[128 * 32];
  f4v acc[4][2];
#pragma unroll
  for (int m = 0; m < 4; ++m)
#pragma unroll
    for (int n = 0; n < 2; ++n) acc[m][n] = f4v{0.f, 0.f, 0.f, 0.f};
  gemm_mainloop8(ctx, Wo, blockIdx.y * 128, blockIdx.x * 128, As, Bs, acc, threadIdx.x);
  const int lane = threadIdx.x & 63, wid = threadIdx.x >> 6;
  const int l15 = lane & 15, lg = lane >> 4;
  const int row0 = blockIdx.y * 128 + (wid >> 2) * 64 + lg * 4;
  const int col0 = blockIdx.x * 128 + (wid & 3) * 32 + l15;
#pragma unroll
  for (int n = 0; n < 2; ++n) {
    const int co = col0 + n * 16;
    const float bsv = bo[co];
#pragma unroll
    for (int m = 0; m < 4; ++m)
#pragma unroll
      for (int j = 0; j < 4; ++j) {
        const int rr = row0 + m * 16 + j;
        out[rr * 1024 + co] = acc[m][n][j] + bsv;
      }
  }
}

// ---------------- flash attention: QBLK=256, 16 waves, K/V dbuf, 1 barrier/chunk ----------------
// grid 256 (b innermost in XCD swizzle), 1024 threads = 16 waves x 16 f-rows.
// Staging: waves 0-7 fill Ks, waves 8-15 fill Vs -> ONE gload16/thread/chunk.
__global__ __launch_bounds__(1024) void attn_k(
    const USH* __restrict__ qh, const USH* __restrict__ kh, const USH* __restrict__ vT,
    const float* __restrict__ rb, const unsigned* __restrict__ maskp, USH* __restrict__ ctx) {
  __shared__ USH Ks[2][64 * 64];        // [t][d], col8 XOR-swizzled by (t&7)
  __shared__ USH Vs[2][64 * 64];        // [d][t], col8 XOR-swizzled by (d&7)
  __shared__ USH Ps[16 * 16 * 72];      // per-wave P[f][t], pad 72 (36 KB)

  const int tid = threadIdx.x, lane = tid & 63, w = tid >> 6;
  const int l15 = lane & 15, lg = lane >> 4;
  // 256 blocks: 32/XCD; b innermost (bias L2 reuse among 4 adjacent blocks)
  const int swz = ((blockIdx.x & 7) << 5) | (blockIdx.x >> 3);
  const int b = swz & 3, fb = (swz >> 2) & 3, h = swz >> 4;
  const int bh = b * 16 + h;

  const int f_row = fb * 256 + w * 16 + l15;              // this lane's f (softmax side)
  const USH* qptr = qh + (bh << 16) + f_row * 64 + lg * 8;
  const s8v bq0 = *(const s8v*)qptr;
  const s8v bq1 = *(const s8v*)(qptr + 32);

  f4v acc[4];                                             // [db]: O[f=lg*4+j][d=db*16+l15]
#pragma unroll
  for (int db = 0; db < 4; ++db) acc[db] = f4v{0.f, 0.f, 0.f, 0.f};
  float m_ = -1e30f, l_ = 0.f;

  const USH* kbase = kh + (bh << 16);
  const USH* vbase = vT + (bh << 16);
  const float* bias_b = rb + (h << 20) + (f_row << 10);
  const unsigned* mask_w = maskp + (((b << 10) + f_row) << 5);  // 32 words per row

  // staging: threads 0-511 fill Ks slots, 512-1023 fill Vs slots (one gload16 each)
  const int st = tid & 511;
  const int kr0 = st >> 3, kc0 = ((st & 7) ^ (kr0 & 7)) * 8;
  const bool is_k = tid < 512;

  // prologue: stage chunk 0 into buf 0; prefetch chunk 0 bias + packed mask
  if (is_k) gload16(kbase + kr0 * 64 + kc0, &Ks[0][st * 8]);
  else      gload16(vbase + kr0 * 1024 + kc0, &Vs[0][st * 8]);
  float4 bv4[4]; uint2 mw;
#pragma unroll
  for (int tb = 0; tb < 4; ++tb)
    bv4[tb] = *(const float4*)(bias_b + tb * 16 + lg * 4);
  mw = *(const uint2*)(mask_w);
  float4 bn4[4]; uint2 mwn;

#pragma unroll 2
  for (int tc = 0; tc < 16; ++tc) {
    const int cur = tc & 1;                               // compile-time under unroll 2
    const int t0 = tc * 64;
    __syncthreads();      // stage(tc) ready (a full chunk in flight); buf[cur^1] free
    if (tc < 15) {
      const int tn = t0 + 64;
      if (is_k) gload16(kbase + (tn + kr0) * 64 + kc0, &Ks[cur ^ 1][st * 8]);
      else      gload16(vbase + kr0 * 1024 + tn + kc0, &Vs[cur ^ 1][st * 8]);
#pragma unroll
      for (int tb = 0; tb < 4; ++tb)
        bn4[tb] = *(const float4*)(bias_b + tn + tb * 16 + lg * 4);
      mwn = *(const uint2*)(mask_w + (tn >> 5));
    }
    // ---- compute chunk tc from buf[cur] ----
    // S^T = K Q^T : lane holds S[t=t0+tb*16+lg*4+j][f=l15]
    f4v sa[4];
    const int sw = (l15 & 7);
    __builtin_amdgcn_s_setprio(1);
#pragma unroll
    for (int tb = 0; tb < 4; ++tb) {
      sa[tb] = f4v{0.f, 0.f, 0.f, 0.f};
      const USH* kp = &Ks[cur][(tb * 16 + l15) * 64];
      sa[tb] = MFMA16(*(const s8v*)(kp + ((lg ^ sw) * 8)), bq0, sa[tb]);
      sa[tb] = MFMA16(*(const s8v*)(kp + (((lg + 4) ^ sw) * 8)), bq1, sa[tb]);
    }
    __builtin_amdgcn_s_setprio(0);
    const unsigned u0 = mw.x >> (lg * 4);
    const unsigned u1 = mw.y >> (lg * 4);
    float sv[4][4];
#pragma unroll
    for (int tb = 0; tb < 4; ++tb) {
      const float* bvp = (const float*)&bv4[tb];
      const unsigned uu = (tb < 2) ? u0 : u1;
      const int sh = (tb & 1) * 16;
#pragma unroll
      for (int j = 0; j < 4; ++j)
        sv[tb][j] = ((uu >> (sh + j)) & 1u) ? -10000.f : fmaf(sa[tb][j], 0.125f, bvp[j]);
    }
    // defer-max online softmax
    float mx = sv[0][0];
#pragma unroll
    for (int tb = 0; tb < 4; ++tb)
#pragma unroll
      for (int j = 0; j < 4; ++j) mx = fmaxf(mx, sv[tb][j]);
    const bool grow = !__all(mx - m_ <= 8.0f);            // wave-uniform
    float al = 1.f;
    if (grow) {
      mx = fmaxf(mx, __shfl_xor(mx, 16));
      mx = fmaxf(mx, __shfl_xor(mx, 32));
      const float mn = fmaxf(m_, mx);
      al = __expf(m_ - mn);
      m_ = mn;
    }
    float rs = 0.f;
    USH* Pw = Ps + w * 1152 + l15 * 72;
#pragma unroll
    for (int tb = 0; tb < 4; ++tb) {
      float p0 = __expf(sv[tb][0] - m_), p1 = __expf(sv[tb][1] - m_);
      float p2 = __expf(sv[tb][2] - m_), p3 = __expf(sv[tb][3] - m_);
      rs += (p0 + p1) + (p2 + p3);
      uint2 pk;
      pk.x = cvtpk(p0, p1);
      pk.y = cvtpk(p2, p3);
      *(uint2*)(Pw + tb * 16 + lg * 4) = pk;
    }
    rs += __shfl_xor(rs, 16);
    rs += __shfl_xor(rs, 32);
    l_ = l_ * al + rs;
    if (grow) {
      const int rbase = (lane >> 4) << 2;
      const f4v alf = {__shfl(al, rbase), __shfl(al, rbase + 1),
                       __shfl(al, rbase + 2), __shfl(al, rbase + 3)};
#pragma unroll
      for (int db = 0; db < 4; ++db) acc[db] = acc[db] * alf;
    }
    // O += P V
    {
      const USH* Pr = Ps + w * 1152 + l15 * 72 + lg * 8;
      const s8v pa0 = *(const s8v*)Pr;
      const s8v pa1 = *(const s8v*)(Pr + 32);
      __builtin_amdgcn_s_setprio(1);
#pragma unroll
      for (int db = 0; db < 4; ++db) {
        const USH* vp = &Vs[cur][(db * 16 + l15) * 64];
        acc[db] = MFMA16(pa0, *(const s8v*)(vp + ((lg ^ sw) * 8)), acc[db]);
        acc[db] = MFMA16(pa1, *(const s8v*)(vp + (((lg + 4) ^ sw) * 8)), acc[db]);
      }
      __builtin_amdgcn_s_setprio(0);
    }
#pragma unroll
    for (int tb = 0; tb < 4; ++tb) bv4[tb] = bn4[tb];
    mw = mwn;
  }
  // epilogue: ctx[b][f][h*64+d]
  const int rbase = (lane >> 4) << 2;
  float inv[4];
#pragma unroll
  for (int j = 0; j < 4; ++j) inv[j] = 1.f / __shfl(l_, rbase + j);
  USH* cbase = ctx + ((size_t)((b << 10) + fb * 256 + w * 16 + lg * 4)) * 1024 + (h << 6) + l15;
#pragma unroll
  for (int db = 0; db < 4; ++db)
#pragma unroll
    for (int j = 0; j < 4; ++j)
      cbase[j * 1024 + db * 16] = f2bf(acc[db][j] * inv[j]);
}

// ---------------- launch ----------------
extern "C" void kernel_launch(void* const* d_in, const int* in_sizes, int n_in,
                              void* d_out, int out_size, void* d_ws, size_t ws_size,
                              hipStream_t stream) {
  const float* q    = (const float*)d_in[0];
  const float* k    = (const float*)d_in[1];
  const float* v    = (const float*)d_in[2];
  const int*   mask = (const int*)d_in[3];
  const float* rb   = (const float*)d_in[4];
  const float* Wq   = (const float*)d_in[5];
  const float* bq   = (const float*)d_in[6];
  const float* Wk   = (const float*)d_in[7];
  const float* bk   = (const float*)d_in[8];
  const float* Wv   = (const float*)d_in[9];
  const float* bv   = (const float*)d_in[10];
  const float* Wo   = (const float*)d_in[11];
  const float* bo   = (const float*)d_in[12];

  char* ws = (char*)d_ws;
  const size_t MB = 1024 * 1024;
  if (ws_size < 65 * MB) return;
  USH* qb    = (USH*)(ws + 0 * MB);
  USH* kb    = (USH*)(ws + 8 * MB);
  USH* vb    = (USH*)(ws + 16 * MB);
  USH* Wqb   = (USH*)(ws + 24 * MB);
  USH* Wkb   = (USH*)(ws + 26 * MB);
  USH* Wvb   = (USH*)(ws + 28 * MB);
  USH* Wob   = (USH*)(ws + 30 * MB);   // [30,32) — 2 MB, do NOT overlap!
  USH* qhp   = (USH*)(ws + 32 * MB);   // [B,H,F,64]
  USH* khp   = (USH*)(ws + 40 * MB);   // [B,H,T,64]
  USH* vTp   = (USH*)(ws + 48 * MB);   // [B,H,64,T]
  USH* ctxp  = (USH*)(ws + 56 * MB);   // [B,F,C] — [56,64)
  unsigned* maskp = (unsigned*)(ws + 64 * MB); // [B,F,32] packed (512 KB), AFTER ctxp

  cvt_all_k<<<dim3(4096, 8), 256, 0, stream>>>(q, k, v, Wq, Wk, Wv, Wo, mask,
                                               qb, kb, vb, Wqb, Wkb, Wvb, Wob, maskp);
  proj_gemm_k<<<dim3(8, 32, 3), 512, 0, stream>>>(qb, kb, vb, Wqb, Wkb, Wvb, bq, bk, bv,
                                                  qhp, khp, vTp);
  attn_k<<<dim3(256), 1024, 0, stream>>>(qhp, khp, vTp, rb, maskp, ctxp);
  out_gemm_k<<<dim3(8, 32), 512, 0, stream>>>(ctxp, Wob, bo, (float*)d_out);
}

// Round 27
// 140.603 us; speedup vs baseline: 1.0335x; 1.0335x over previous
//
#include <hip/hip_runtime.h>

#define USH unsigned short

using s8v = __attribute__((ext_vector_type(8))) short;   // 8 x bf16 (4 VGPR)
using f4v = __attribute__((ext_vector_type(4))) float;   // MFMA accumulator

#define MFMA16(a,b,c) __builtin_amdgcn_mfma_f32_16x16x32_bf16(a,b,c,0,0,0)

// dims: B=4, F=T=1024, C=1024, H=16, D=64

__device__ __forceinline__ USH f2bf(float f) {            // RNE f32->bf16
  unsigned int u = __builtin_bit_cast(unsigned int, f);
  u += 0x7fffu + ((u >> 16) & 1u);
  return (USH)(u >> 16);
}
__device__ __forceinline__ unsigned cvtpk(float lo, float hi) { // 2xf32 -> packed bf16 (RNE)
  unsigned r;
  asm("v_cvt_pk_bf16_f32 %0, %1, %2" : "=v"(r) : "v"(lo), "v"(hi));
  return r;
}
__device__ __forceinline__ void gload16(const void* g, void* l) {
  __builtin_amdgcn_global_load_lds((const __attribute__((address_space(1))) void*)g,
                                   (__attribute__((address_space(3))) void*)l, 16, 0, 0);
}

// ---------------- fused pre-pass: qkv cvt (y=0..2), weight cvt (y=3..6), mask pack (y=7) ----------------
__global__ __launch_bounds__(256) void cvt_all_k(
    const float* __restrict__ q, const float* __restrict__ k, const float* __restrict__ v,
    const float* __restrict__ Wq, const float* __restrict__ Wk,
    const float* __restrict__ Wv, const float* __restrict__ Wo,
    const int* __restrict__ mask,
    USH* __restrict__ oq, USH* __restrict__ ok, USH* __restrict__ ov,
    USH* __restrict__ oWq, USH* __restrict__ oWk, USH* __restrict__ oWv, USH* __restrict__ oWo,
    unsigned* __restrict__ omask) {
  const int which = blockIdx.y;
  const int i = blockIdx.x * 256 + threadIdx.x;
  if (which == 7) {                                       // mask pack: 131072 words
    if (i >= 131072) return;
    const int4* p = (const int4*)(mask + i * 32);
    unsigned m = 0;
#pragma unroll
    for (int qq = 0; qq < 8; ++qq) {
      int4 vv = p[qq];
      m |= (unsigned)(vv.x != 0) << (qq * 4);
      m |= (unsigned)(vv.y != 0) << (qq * 4 + 1);
      m |= (unsigned)(vv.z != 0) << (qq * 4 + 2);
      m |= (unsigned)(vv.w != 0) << (qq * 4 + 3);
    }
    omask[i] = m;
    return;
  }
  const float* in; USH* out; int n4;
  switch (which) {
    case 0: in = q;  out = oq;  n4 = 1 << 20; break;
    case 1: in = k;  out = ok;  n4 = 1 << 20; break;
    case 2: in = v;  out = ov;  n4 = 1 << 20; break;
    case 3: in = Wq; out = oWq; n4 = 1 << 18; break;
    case 4: in = Wk; out = oWk; n4 = 1 << 18; break;
    case 5: in = Wv; out = oWv; n4 = 1 << 18; break;
    default: in = Wo; out = oWo; n4 = 1 << 18; break;
  }
  if (i >= n4) return;
  float4 val = ((const float4*)in)[i];
  ushort4 o; o.x = f2bf(val.x); o.y = f2bf(val.y); o.z = f2bf(val.z); o.w = f2bf(val.w);
  ((ushort4*)out)[i] = o;
}

// ---------------- GEMM core: 128x128 tile, BK=32, 512 threads = 8 waves (2x4), B^T layout ----------------
__device__ __forceinline__ void gemm_mainloop8(
    const USH* __restrict__ A, const USH* __restrict__ W,
    int rowA0, int colW0, USH* As, USH* Bs, f4v acc[4][2], int tid) {
  const int lane = tid & 63;
  const int wid = tid >> 6;
  const int l15 = lane & 15, lg = lane >> 4;
  const int wr = (wid >> 2) * 64, wc = (wid & 3) * 32;
  const int srow = tid >> 2, scol = (tid & 3) * 8;
  for (int kk = 0; kk < 32; ++kk) {
    const int k0 = kk * 32;
    gload16(A + (rowA0 + srow) * 1024 + k0 + scol, As + tid * 8);
    gload16(W + (colW0 + srow) * 1024 + k0 + scol, Bs + tid * 8);
    __syncthreads();
    s8v a[4], b[2];
    const USH* ap = As + (wr + l15) * 32 + lg * 8;
    const USH* bp = Bs + (wc + l15) * 32 + lg * 8;
#pragma unroll
    for (int m = 0; m < 4; ++m) a[m] = *(const s8v*)(ap + m * 512);
#pragma unroll
    for (int n = 0; n < 2; ++n) b[n] = *(const s8v*)(bp + n * 512);
#pragma unroll
    for (int m = 0; m < 4; ++m)
#pragma unroll
      for (int n = 0; n < 2; ++n)
        acc[m][n] = MFMA16(a[m], b[n], acc[m][n]);
    __syncthreads();
  }
}

// fused Q/K/V projection; z selects which. Q/K -> [B,H,S,64]; V -> [B,H,64,T] (transposed)
__global__ __launch_bounds__(512) void proj_gemm_k(
    const USH* __restrict__ qb, const USH* __restrict__ kb, const USH* __restrict__ vb,
    const USH* __restrict__ Wq, const USH* __restrict__ Wk, const USH* __restrict__ Wv,
    const float* __restrict__ bq, const float* __restrict__ bk, const float* __restrict__ bv,
    USH* __restrict__ qh, USH* __restrict__ kh, USH* __restrict__ vT) {
  __shared__ USH As[128 * 32];
  __shared__ USH Bs[128 * 32];
  const int z = blockIdx.z;
  const USH* A = z == 0 ? qb : (z == 1 ? kb : vb);
  const USH* W = z == 0 ? Wq : (z == 1 ? Wk : Wv);
  const float* bias = z == 0 ? bq : (z == 1 ? bk : bv);
  f4v acc[4][2];
#pragma unroll
  for (int m = 0; m < 4; ++m)
#pragma unroll
    for (int n = 0; n < 2; ++n) acc[m][n] = f4v{0.f, 0.f, 0.f, 0.f};
  gemm_mainloop8(A, W, blockIdx.y * 128, blockIdx.x * 128, As, Bs, acc, threadIdx.x);
  const int lane = threadIdx.x & 63, wid = threadIdx.x >> 6;
  const int l15 = lane & 15, lg = lane >> 4;
  const int row0 = blockIdx.y * 128 + (wid >> 2) * 64 + lg * 4;
  const int col0 = blockIdx.x * 128 + (wid & 3) * 32 + l15;
  USH* qk_dst = (z == 0) ? qh : kh;
#pragma unroll
  for (int n = 0; n < 2; ++n) {
    const int co = col0 + n * 16;
    const float bsv = bias[co];
    const int hh = co >> 6, d = co & 63;
#pragma unroll
    for (int m = 0; m < 4; ++m)
#pragma unroll
      for (int j = 0; j < 4; ++j) {
        const int rr = row0 + m * 16 + j;
        const float v = acc[m][n][j] + bsv;
        const int bb = rr >> 10, s = rr & 1023;
        if (z < 2) qk_dst[((bb * 16 + hh) << 16) + (s << 6) + d] = f2bf(v);
        else       vT[((bb * 16 + hh) << 16) + (d << 10) + s] = f2bf(v);
      }
  }
}

// output projection: d_out = ctx @ Wo^T + bo  (f32 out)
__global__ __launch_bounds__(512) void out_gemm_k(
    const USH* __restrict__ ctx, const USH* __restrict__ Wo,
    const float* __restrict__ bo, float* __restrict__ out) {
  __shared__ USH As[128 * 32];
  __shared__ USH Bs[128 * 32];
  f4v acc[4][2];
#pragma unroll
  for (int m = 0; m < 4; ++m)
#pragma unroll
    for (int n = 0; n < 2; ++n) acc[m][n] = f4v{0.f, 0.f, 0.f, 0.f};
  gemm_mainloop8(ctx, Wo, blockIdx.y * 128, blockIdx.x * 128, As, Bs, acc, threadIdx.x);
  const int lane = threadIdx.x & 63, wid = threadIdx.x >> 6;
  const int l15 = lane & 15, lg = lane >> 4;
  const int row0 = blockIdx.y * 128 + (wid >> 2) * 64 + lg * 4;
  const int col0 = blockIdx.x * 128 + (wid & 3) * 32 + l15;
#pragma unroll
  for (int n = 0; n < 2; ++n) {
    const int co = col0 + n * 16;
    const float bsv = bo[co];
#pragma unroll
    for (int m = 0; m < 4; ++m)
#pragma unroll
      for (int j = 0; j < 4; ++j) {
        const int rr = row0 + m * 16 + j;
        out[rr * 1024 + co] = acc[m][n][j] + bsv;
      }
  }
}

// ---------------- flash attention: QBLK=256, 16 waves, K/V dbuf, 1 barrier/chunk ----------------
// grid 256 (b innermost in XCD swizzle), 1024 threads = 16 waves x 16 f-rows.
// Staging: waves 0-7 fill Ks, waves 8-15 fill Vs -> ONE gload16/thread/chunk.
__global__ __launch_bounds__(1024) void attn_k(
    const USH* __restrict__ qh, const USH* __restrict__ kh, const USH* __restrict__ vT,
    const float* __restrict__ rb, const unsigned* __restrict__ maskp, USH* __restrict__ ctx) {
  __shared__ USH Ks[2][64 * 64];        // [t][d], col8 XOR-swizzled by (t&7)
  __shared__ USH Vs[2][64 * 64];        // [d][t], col8 XOR-swizzled by (d&7)
  __shared__ USH Ps[16 * 16 * 72];      // per-wave P[f][t], pad 72 (36 KB)

  const int tid = threadIdx.x, lane = tid & 63, w = tid >> 6;
  const int l15 = lane & 15, lg = lane >> 4;
  // 256 blocks: 32/XCD; b innermost (bias L2 reuse among 4 adjacent blocks)
  const int swz = ((blockIdx.x & 7) << 5) | (blockIdx.x >> 3);
  const int b = swz & 3, fb = (swz >> 2) & 3, h = swz >> 4;
  const int bh = b * 16 + h;

  const int f_row = fb * 256 + w * 16 + l15;              // this lane's f (softmax side)
  const USH* qptr = qh + (bh << 16) + f_row * 64 + lg * 8;
  const s8v bq0 = *(const s8v*)qptr;
  const s8v bq1 = *(const s8v*)(qptr + 32);

  f4v acc[4];                                             // [db]: O[f=lg*4+j][d=db*16+l15]
#pragma unroll
  for (int db = 0; db < 4; ++db) acc[db] = f4v{0.f, 0.f, 0.f, 0.f};
  float m_ = -1e30f, l_ = 0.f;

  const USH* kbase = kh + (bh << 16);
  const USH* vbase = vT + (bh << 16);
  const float* bias_b = rb + (h << 20) + (f_row << 10);
  const unsigned* mask_w = maskp + (((b << 10) + f_row) << 5);  // 32 words per row

  // staging: threads 0-511 fill Ks slots, 512-1023 fill Vs slots (one gload16 each)
  const int st = tid & 511;
  const int kr0 = st >> 3, kc0 = ((st & 7) ^ (kr0 & 7)) * 8;
  const bool is_k = tid < 512;

  // prologue: stage chunk 0 into buf 0; prefetch chunk 0 bias + packed mask
  if (is_k) gload16(kbase + kr0 * 64 + kc0, &Ks[0][st * 8]);
  else      gload16(vbase + kr0 * 1024 + kc0, &Vs[0][st * 8]);
  float4 bv4[4]; uint2 mw;
#pragma unroll
  for (int tb = 0; tb < 4; ++tb)
    bv4[tb] = *(const float4*)(bias_b + tb * 16 + lg * 4);
  mw = *(const uint2*)(mask_w);
  float4 bn4[4]; uint2 mwn;

#pragma unroll 2
  for (int tc = 0; tc < 16; ++tc) {
    const int cur = tc & 1;                               // compile-time under unroll 2
    const int t0 = tc * 64;
    __syncthreads();      // stage(tc) ready (a full chunk in flight); buf[cur^1] free
    if (tc < 15) {
      const int tn = t0 + 64;
      if (is_k) gload16(kbase + (tn + kr0) * 64 + kc0, &Ks[cur ^ 1][st * 8]);
      else      gload16(vbase + kr0 * 1024 + tn + kc0, &Vs[cur ^ 1][st * 8]);
#pragma unroll
      for (int tb = 0; tb < 4; ++tb)
        bn4[tb] = *(const float4*)(bias_b + tn + tb * 16 + lg * 4);
      mwn = *(const uint2*)(mask_w + (tn >> 5));
    }
    // ---- compute chunk tc from buf[cur] ----
    // S^T = K Q^T : lane holds S[t=t0+tb*16+lg*4+j][f=l15]
    f4v sa[4];
    const int sw = (l15 & 7);
    __builtin_amdgcn_s_setprio(1);
#pragma unroll
    for (int tb = 0; tb < 4; ++tb) {
      sa[tb] = f4v{0.f, 0.f, 0.f, 0.f};
      const USH* kp = &Ks[cur][(tb * 16 + l15) * 64];
      sa[tb] = MFMA16(*(const s8v*)(kp + ((lg ^ sw) * 8)), bq0, sa[tb]);
      sa[tb] = MFMA16(*(const s8v*)(kp + (((lg + 4) ^ sw) * 8)), bq1, sa[tb]);
    }
    __builtin_amdgcn_s_setprio(0);
    const unsigned u0 = mw.x >> (lg * 4);
    const unsigned u1 = mw.y >> (lg * 4);
    float sv[4][4];
#pragma unroll
    for (int tb = 0; tb < 4; ++tb) {
      const float* bvp = (const float*)&bv4[tb];
      const unsigned uu = (tb < 2) ? u0 : u1;
      const int sh = (tb & 1) * 16;
#pragma unroll
      for (int j = 0; j < 4; ++j)
        sv[tb][j] = ((uu >> (sh + j)) & 1u) ? -10000.f : fmaf(sa[tb][j], 0.125f, bvp[j]);
    }
    // defer-max online softmax
    float mx = sv[0][0];
#pragma unroll
    for (int tb = 0; tb < 4; ++tb)
#pragma unroll
      for (int j = 0; j < 4; ++j) mx = fmaxf(mx, sv[tb][j]);
    const bool grow = !__all(mx - m_ <= 8.0f);            // wave-uniform
    float al = 1.f;
    if (grow) {
      mx = fmaxf(mx, __shfl_xor(mx, 16));
      mx = fmaxf(mx, __shfl_xor(mx, 32));
      const float mn = fmaxf(m_, mx);
      al = __expf(m_ - mn);
      m_ = mn;
    }
    float rs = 0.f;
    USH* Pw = Ps + w * 1152 + l15 * 72;
#pragma unroll
    for (int tb = 0; tb < 4; ++tb) {
      float p0 = __expf(sv[tb][0] - m_), p1 = __expf(sv[tb][1] - m_);
      float p2 = __expf(sv[tb][2] - m_), p3 = __expf(sv[tb][3] - m_);
      rs += (p0 + p1) + (p2 + p3);
      uint2 pk;
      pk.x = cvtpk(p0, p1);
      pk.y = cvtpk(p2, p3);
      *(uint2*)(Pw + tb * 16 + lg * 4) = pk;
    }
    rs += __shfl_xor(rs, 16);
    rs += __shfl_xor(rs, 32);
    l_ = l_ * al + rs;
    if (grow) {
      const int rbase = (lane >> 4) << 2;
      const f4v alf = {__shfl(al, rbase), __shfl(al, rbase + 1),
                       __shfl(al, rbase + 2), __shfl(al, rbase + 3)};
#pragma unroll
      for (int db = 0; db < 4; ++db) acc[db] = acc[db] * alf;
    }
    // O += P V
    {
      const USH* Pr = Ps + w * 1152 + l15 * 72 + lg * 8;
      const s8v pa0 = *(const s8v*)Pr;
      const s8v pa1 = *(const s8v*)(Pr + 32);
      __builtin_amdgcn_s_setprio(1);
#pragma unroll
      for (int db = 0; db < 4; ++db) {
        const USH* vp = &Vs[cur][(db * 16 + l15) * 64];
        acc[db] = MFMA16(pa0, *(const s8v*)(vp + ((lg ^ sw) * 8)), acc[db]);
        acc[db] = MFMA16(pa1, *(const s8v*)(vp + (((lg + 4) ^ sw) * 8)), acc[db]);
      }
      __builtin_amdgcn_s_setprio(0);
    }
#pragma unroll
    for (int tb = 0; tb < 4; ++tb) bv4[tb] = bn4[tb];
    mw = mwn;
  }
  // epilogue: ctx[b][f][h*64+d]
  const int rbase = (lane >> 4) << 2;
  float inv[4];
#pragma unroll
  for (int j = 0; j < 4; ++j) inv[j] = 1.f / __shfl(l_, rbase + j);
  USH* cbase = ctx + ((size_t)((b << 10) + fb * 256 + w * 16 + lg * 4)) * 1024 + (h << 6) + l15;
#pragma unroll
  for (int db = 0; db < 4; ++db)
#pragma unroll
    for (int j = 0; j < 4; ++j)
      cbase[j * 1024 + db * 16] = f2bf(acc[db][j] * inv[j]);
}

// ---------------- launch ----------------
extern "C" void kernel_launch(void* const* d_in, const int* in_sizes, int n_in,
                              void* d_out, int out_size, void* d_ws, size_t ws_size,
                              hipStream_t stream) {
  const float* q    = (const float*)d_in[0];
  const float* k    = (const float*)d_in[1];
  const float* v    = (const float*)d_in[2];
  const int*   mask = (const int*)d_in[3];
  const float* rb   = (const float*)d_in[4];
  const float* Wq   = (const float*)d_in[5];
  const float* bq   = (const float*)d_in[6];
  const float* Wk   = (const float*)d_in[7];
  const float* bk   = (const float*)d_in[8];
  const float* Wv   = (const float*)d_in[9];
  const float* bv   = (const float*)d_in[10];
  const float* Wo   = (const float*)d_in[11];
  const float* bo   = (const float*)d_in[12];

  char* ws = (char*)d_ws;
  const size_t MB = 1024 * 1024;
  if (ws_size < 65 * MB) return;
  USH* qb    = (USH*)(ws + 0 * MB);
  USH* kb    = (USH*)(ws + 8 * MB);
  USH* vb    = (USH*)(ws + 16 * MB);
  USH* Wqb   = (USH*)(ws + 24 * MB);
  USH* Wkb   = (USH*)(ws + 26 * MB);
  USH* Wvb   = (USH*)(ws + 28 * MB);
  USH* Wob   = (USH*)(ws + 30 * MB);   // [30,32) — 2 MB, do NOT overlap!
  USH* qhp   = (USH*)(ws + 32 * MB);   // [B,H,F,64]
  USH* khp   = (USH*)(ws + 40 * MB);   // [B,H,T,64]
  USH* vTp   = (USH*)(ws + 48 * MB);   // [B,H,64,T]
  USH* ctxp  = (USH*)(ws + 56 * MB);   // [B,F,C] — [56,64)
  unsigned* maskp = (unsigned*)(ws + 64 * MB); // [B,F,32] packed (512 KB), AFTER ctxp

  cvt_all_k<<<dim3(4096, 8), 256, 0, stream>>>(q, k, v, Wq, Wk, Wv, Wo, mask,
                                               qb, kb, vb, Wqb, Wkb, Wvb, Wob, maskp);
  proj_gemm_k<<<dim3(8, 32, 3), 512, 0, stream>>>(qb, kb, vb, Wqb, Wkb, Wvb, bq, bk, bv,
                                                  qhp, khp, vTp);
  attn_k<<<dim3(256), 1024, 0, stream>>>(qhp, khp, vTp, rb, maskp, ctxp);
  out_gemm_k<<<dim3(8, 32), 512, 0, stream>>>(ctxp, Wob, bo, (float*)d_out);
}